// Round 3
// baseline (295.105 us; speedup 1.0000x reference)
//
#include <hip/hip_runtime.h>

#define S_DIM 2048
#define K_DIM 4096
#define O_DIM 4096
#define NNON  3968   // H - KEEPER
#define NB    31     // low-precision blocks

#define XBLK 8192    // scale_x segment blocks:  S*K/4/256
#define WBLK 16384   // scale_w segment blocks:  O*K/4/256
#define ZBLK 8192    // zero-C segment blocks:   S*O/4/256

typedef __bf16 bf16x8 __attribute__((ext_vector_type(8)));
typedef float  f32x4  __attribute__((ext_vector_type(4)));

__device__ __forceinline__ unsigned short f2bf(float f) {
    union { float f; unsigned u; } v; v.f = f;
    unsigned r = v.u + 0x7FFFu + ((v.u >> 16) & 1u);   // round-to-nearest-even
    return (unsigned short)(r >> 16);
}

// One fused prepass launch, three block-uniform segments:
//   [0, XBLK)           A'[s,k] = bf16(x * sc_lo/hi)
//   [XBLK, XBLK+WBLK)   B'[o,k] = bf16(w * scales/keep)
//   [.., +ZBLK)         C = 0   (required: gemm epilogue is atomicAdd)
__global__ __launch_bounds__(256) void prepass(const float* __restrict__ x,
                                               const float* __restrict__ sc_lo,
                                               const float* __restrict__ sc_hi,
                                               const float* __restrict__ w,
                                               const float* __restrict__ scales,
                                               const float* __restrict__ keep,
                                               unsigned short* __restrict__ A,
                                               unsigned short* __restrict__ B,
                                               float* __restrict__ C)
{
    const int b = blockIdx.x;
    if (b < XBLK) {
        int idx = b * 256 + threadIdx.x;           // over S*K/4, K/4 = 1024
        int s = idx >> 10;
        int k = (idx & 1023) << 2;                 // 4 elems never straddle a 128-block
        float4 v = ((const float4*)x)[idx];
        float sc = (k < NNON) ? sc_lo[s * NB + (k >> 7)] : sc_hi[s];
        ushort4 o;
        o.x = f2bf(v.x * sc); o.y = f2bf(v.y * sc);
        o.z = f2bf(v.z * sc); o.w = f2bf(v.w * sc);
        ((ushort4*)A)[idx] = o;
    } else if (b < XBLK + WBLK) {
        int idx = (b - XBLK) * 256 + threadIdx.x;  // over O*K/4
        int o = idx >> 10;
        int k = (idx & 1023) << 2;
        float4 v = ((const float4*)w)[idx];
        float sc = (k < NNON) ? scales[(size_t)o * NNON + ((k >> 7) << 7)] : keep[o];
        ushort4 r;
        r.x = f2bf(v.x * sc); r.y = f2bf(v.y * sc);
        r.z = f2bf(v.z * sc); r.w = f2bf(v.w * sc);
        ((ushort4*)B)[idx] = r;
    } else {
        int idx = (b - XBLK - WBLK) * 256 + threadIdx.x;  // over S*O/4
        ((float4*)C)[idx] = make_float4(0.f, 0.f, 0.f, 0.f);
    }
}

// NT GEMM, split-K=2: A [M,K] bf16, B [N,K] bf16 (B^T layout), C [M,N] f32.
// 128x128 block tile, BK=64, 4 waves 2x2, each wave 4x4 of 16x16x32 MFMAs
// x2 k-steps per staging tile. blockIdx.z picks the K-half; epilogue is
// unsafeAtomicAdd (HW global_atomic_add_f32; 2 commutative adds onto zero
// -> bitwise deterministic). Grid 1024 blocks -> 4 blocks/CU (was 2, the
// R2 occupancy cap).
// LDS XOR swizzle (R2-verified, conflicts 8.4M -> 0): 16B chunk at logical
// (row, c) stored at chunk position c ^ (row & 7); applied on the global
// source address during global_load_lds staging, un-permuted on ds_read.
#define BM 128
#define BN 128
#define BK 64
#define KSPLIT 2
#define KHALF (K_DIM / KSPLIT)

__global__ __launch_bounds__(256) void gemm_bt(const unsigned short* __restrict__ A,
                                               const unsigned short* __restrict__ B,
                                               float* __restrict__ C)
{
    __shared__ unsigned short As[BM * BK];   // 16 KB
    __shared__ unsigned short Bs[BN * BK];   // 16 KB

    const int tid  = threadIdx.x;
    const int wave = tid >> 6;
    const int lane = tid & 63;
    const int quad = lane >> 4;
    const int l16  = lane & 15;
    const int bm = blockIdx.y * BM;
    const int bn = blockIdx.x * BN;
    const int kz = blockIdx.z;
    const int wm = (wave >> 1) * 64;
    const int wn = (wave & 1) * 64;

    const int srow = (lane >> 3);                       // 0..7 within chunk
    const int scol = (((lane & 7) ^ (srow & 7)) << 3);  // swizzled global col
    const int swz  = (l16 & 7);                         // reader-side XOR key

    f32x4 acc[4][4];
    #pragma unroll
    for (int i = 0; i < 4; ++i)
        #pragma unroll
        for (int j = 0; j < 4; ++j)
            acc[i][j] = (f32x4){0.f, 0.f, 0.f, 0.f};

    const int kbeg = kz * KHALF;
    for (int k0 = kbeg; k0 < kbeg + KHALF; k0 += BK) {
        __syncthreads();   // previous tile's reads done before overwrite
        #pragma unroll
        for (int c = 0; c < 4; ++c) {
            const int row = wave * 32 + c * 8 + srow;
            __builtin_amdgcn_global_load_lds(
                (__attribute__((address_space(1))) unsigned int*)(A + (size_t)(bm + row) * K_DIM + k0 + scol),
                (__attribute__((address_space(3))) unsigned int*)(&As[(wave * 4 + c) * 512]),
                16, 0, 0);
            __builtin_amdgcn_global_load_lds(
                (__attribute__((address_space(1))) unsigned int*)(B + (size_t)(bn + row) * K_DIM + k0 + scol),
                (__attribute__((address_space(3))) unsigned int*)(&Bs[(wave * 4 + c) * 512]),
                16, 0, 0);
        }
        __syncthreads();

        #pragma unroll
        for (int ks = 0; ks < 2; ++ks) {
            bf16x8 af[4], bfr[4];
            #pragma unroll
            for (int i = 0; i < 4; ++i)
                af[i] = *(const bf16x8*)(&As[(wm + i * 16 + l16) * BK + (((ks * 4 + quad) ^ swz) << 3)]);
            #pragma unroll
            for (int j = 0; j < 4; ++j)
                bfr[j] = *(const bf16x8*)(&Bs[(wn + j * 16 + l16) * BK + (((ks * 4 + quad) ^ swz) << 3)]);
            #pragma unroll
            for (int i = 0; i < 4; ++i)
                #pragma unroll
                for (int j = 0; j < 4; ++j)
                    acc[i][j] = __builtin_amdgcn_mfma_f32_16x16x32_bf16(af[i], bfr[j], acc[i][j], 0, 0, 0);
        }
    }

    // C/D layout (m89-verified): col = lane&15, row = quad*4 + reg
    #pragma unroll
    for (int i = 0; i < 4; ++i)
        #pragma unroll
        for (int j = 0; j < 4; ++j) {
            const int col = bn + wn + j * 16 + l16;
            #pragma unroll
            for (int r = 0; r < 4; ++r) {
                const int row = bm + wm + i * 16 + quad * 4 + r;
                unsafeAtomicAdd(&C[(size_t)row * O_DIM + col], acc[i][j][r]);
            }
        }
}

extern "C" void kernel_launch(void* const* d_in, const int* in_sizes, int n_in,
                              void* d_out, int out_size, void* d_ws, size_t ws_size,
                              hipStream_t stream) {
    const float* x      = (const float*)d_in[0];
    const float* weight = (const float*)d_in[1];  // [O, K]
    const float* scales = (const float*)d_in[2];  // [O, NNON]
    const float* keep   = (const float*)d_in[3];  // [O, 1]
    const float* sc_lo  = (const float*)d_in[4];  // [S, NB]
    const float* sc_hi  = (const float*)d_in[5];  // [S, 1]
    // d_in[6], d_in[7] (inp_base_lo/hi) unused by reference

    // workspace: A' 16 MB @ 0, B' 32 MB @ 16 MB (needs 48 MB of d_ws)
    unsigned short* A = (unsigned short*)d_ws;
    unsigned short* B = A + (size_t)S_DIM * K_DIM;
    float* C = (float*)d_out;

    prepass<<<XBLK + WBLK + ZBLK, 256, 0, stream>>>(x, sc_lo, sc_hi, weight, scales, keep, A, B, C);

    dim3 grid(O_DIM / BN, S_DIM / BM, KSPLIT);
    gemm_bt<<<grid, 256, 0, stream>>>(A, B, C);
}

// Round 4
// 246.776 us; speedup vs baseline: 1.1958x; 1.1958x over previous
//
#include <hip/hip_runtime.h>

#define S_DIM 2048
#define K_DIM 4096
#define O_DIM 4096
#define NNON  3968   // H - KEEPER
#define NB    31     // low-precision blocks

#define XBLK 8192    // scale_x segment blocks:  S*K/4/256
#define WBLK 16384   // scale_w segment blocks:  O*K/4/256

typedef __bf16 bf16x8 __attribute__((ext_vector_type(8)));
typedef float  f32x4  __attribute__((ext_vector_type(4)));

__device__ __forceinline__ unsigned short f2bf(float f) {
    union { float f; unsigned u; } v; v.f = f;
    unsigned r = v.u + 0x7FFFu + ((v.u >> 16) & 1u);   // round-to-nearest-even
    return (unsigned short)(r >> 16);
}

// One fused prepass launch, two block-uniform segments:
//   [0, XBLK)           A'[s,k] = bf16(x * sc_lo/hi)
//   [XBLK, XBLK+WBLK)   B'[o,k] = bf16(w * scales/keep)
__global__ __launch_bounds__(256) void prepass(const float* __restrict__ x,
                                               const float* __restrict__ sc_lo,
                                               const float* __restrict__ sc_hi,
                                               const float* __restrict__ w,
                                               const float* __restrict__ scales,
                                               const float* __restrict__ keep,
                                               unsigned short* __restrict__ A,
                                               unsigned short* __restrict__ B)
{
    const int b = blockIdx.x;
    if (b < XBLK) {
        int idx = b * 256 + threadIdx.x;           // over S*K/4, K/4 = 1024
        int s = idx >> 10;
        int k = (idx & 1023) << 2;                 // 4 elems never straddle a 128-block
        float4 v = ((const float4*)x)[idx];
        float sc = (k < NNON) ? sc_lo[s * NB + (k >> 7)] : sc_hi[s];
        ushort4 o;
        o.x = f2bf(v.x * sc); o.y = f2bf(v.y * sc);
        o.z = f2bf(v.z * sc); o.w = f2bf(v.w * sc);
        ((ushort4*)A)[idx] = o;
    } else {
        int idx = (b - XBLK) * 256 + threadIdx.x;  // over O*K/4
        int o = idx >> 10;
        int k = (idx & 1023) << 2;
        float4 v = ((const float4*)w)[idx];
        float sc = (k < NNON) ? scales[(size_t)o * NNON + ((k >> 7) << 7)] : keep[o];
        ushort4 r;
        r.x = f2bf(v.x * sc); r.y = f2bf(v.y * sc);
        r.z = f2bf(v.z * sc); r.w = f2bf(v.w * sc);
        ((ushort4*)B)[idx] = r;
    }
}

// NT GEMM: A [M,K] bf16, B [N,K] bf16 (B^T layout), C [M,N] f32.
// 128x128 block tile, BK=64, 4 waves 2x2, each wave 4x4 of 16x16x32 MFMAs
// x2 k-steps per staging tile. Plain stores (split-K reverted: R3 regression).
// Software pipeline (single LDS buffer):
//   [ds_read frags(k) ; barrier ; issue global_load_lds(k+1) ; MFMA x32 ;
//    barrier w/ vmcnt(0) drain]
// -> the 32 MFMAs issue inside the global-load latency shadow instead of
//    after the drain.
// LDS XOR swizzle (R2-verified, conflicts 8.4M -> 0): 16B chunk at logical
// (row, c) stored at chunk position c ^ (row & 7); applied on the global
// source column during staging, un-permuted on ds_read.
#define BM 128
#define BN 128
#define BK 64

__global__ __launch_bounds__(256) void gemm_bt(const unsigned short* __restrict__ A,
                                               const unsigned short* __restrict__ B,
                                               float* __restrict__ C)
{
    __shared__ unsigned short As[BM * BK];   // 16 KB
    __shared__ unsigned short Bs[BN * BK];   // 16 KB

    const int tid  = threadIdx.x;
    const int wave = tid >> 6;
    const int lane = tid & 63;
    const int quad = lane >> 4;
    const int l16  = lane & 15;
    const int bm = blockIdx.y * BM;
    const int bn = blockIdx.x * BN;
    const int wm = (wave >> 1) * 64;
    const int wn = (wave & 1) * 64;

    const int srow = (lane >> 3);                       // 0..7 within chunk
    const int scol = (((lane & 7) ^ (srow & 7)) << 3);  // swizzled global col
    const int swz  = (l16 & 7);                         // reader-side XOR key

    const unsigned short* Abase = A + (size_t)(bm + wave * 32 + srow) * K_DIM + scol;
    const unsigned short* Bbase = B + (size_t)(bn + wave * 32 + srow) * K_DIM + scol;

    f32x4 acc[4][4];
    #pragma unroll
    for (int i = 0; i < 4; ++i)
        #pragma unroll
        for (int j = 0; j < 4; ++j)
            acc[i][j] = (f32x4){0.f, 0.f, 0.f, 0.f};

    // prologue: stage tile 0
    #pragma unroll
    for (int c = 0; c < 4; ++c) {
        __builtin_amdgcn_global_load_lds(
            (__attribute__((address_space(1))) unsigned int*)(Abase + (size_t)(c * 8) * K_DIM),
            (__attribute__((address_space(3))) unsigned int*)(&As[(wave * 4 + c) * 512]),
            16, 0, 0);
        __builtin_amdgcn_global_load_lds(
            (__attribute__((address_space(1))) unsigned int*)(Bbase + (size_t)(c * 8) * K_DIM),
            (__attribute__((address_space(3))) unsigned int*)(&Bs[(wave * 4 + c) * 512]),
            16, 0, 0);
    }
    __syncthreads();   // vmcnt(0): tile 0 resident

    for (int k0 = 0; k0 < K_DIM; k0 += BK) {
        // LDS -> register fragments for tile k0 (both k-steps up front)
        bf16x8 af[2][4], bfr[2][4];
        #pragma unroll
        for (int ks = 0; ks < 2; ++ks) {
            #pragma unroll
            for (int i = 0; i < 4; ++i)
                af[ks][i] = *(const bf16x8*)(&As[(wm + i * 16 + l16) * BK + (((ks * 4 + quad) ^ swz) << 3)]);
            #pragma unroll
            for (int j = 0; j < 4; ++j)
                bfr[ks][j] = *(const bf16x8*)(&Bs[(wn + j * 16 + l16) * BK + (((ks * 4 + quad) ^ swz) << 3)]);
        }
        __syncthreads();   // all waves done reading LDS (lgkm drained)

        // issue next tile's staging loads; MFMAs below run in their shadow
        if (k0 + BK < K_DIM) {
            const size_t koff = (size_t)(k0 + BK);
            #pragma unroll
            for (int c = 0; c < 4; ++c) {
                __builtin_amdgcn_global_load_lds(
                    (__attribute__((address_space(1))) unsigned int*)(Abase + (size_t)(c * 8) * K_DIM + koff),
                    (__attribute__((address_space(3))) unsigned int*)(&As[(wave * 4 + c) * 512]),
                    16, 0, 0);
                __builtin_amdgcn_global_load_lds(
                    (__attribute__((address_space(1))) unsigned int*)(Bbase + (size_t)(c * 8) * K_DIM + koff),
                    (__attribute__((address_space(3))) unsigned int*)(&Bs[(wave * 4 + c) * 512]),
                    16, 0, 0);
            }
        }

        #pragma unroll
        for (int ks = 0; ks < 2; ++ks)
            #pragma unroll
            for (int i = 0; i < 4; ++i)
                #pragma unroll
                for (int j = 0; j < 4; ++j)
                    acc[i][j] = __builtin_amdgcn_mfma_f32_16x16x32_bf16(af[ks][i], bfr[ks][j], acc[i][j], 0, 0, 0);

        __syncthreads();   // vmcnt(0) drain: tile k0+BK resident
    }

    // C/D layout (m89-verified): col = lane&15, row = quad*4 + reg
    #pragma unroll
    for (int i = 0; i < 4; ++i)
        #pragma unroll
        for (int j = 0; j < 4; ++j) {
            const int col = bn + wn + j * 16 + l16;
            #pragma unroll
            for (int r = 0; r < 4; ++r) {
                const int row = bm + wm + i * 16 + quad * 4 + r;
                C[(size_t)row * O_DIM + col] = acc[i][j][r];
            }
        }
}

extern "C" void kernel_launch(void* const* d_in, const int* in_sizes, int n_in,
                              void* d_out, int out_size, void* d_ws, size_t ws_size,
                              hipStream_t stream) {
    const float* x      = (const float*)d_in[0];
    const float* weight = (const float*)d_in[1];  // [O, K]
    const float* scales = (const float*)d_in[2];  // [O, NNON]
    const float* keep   = (const float*)d_in[3];  // [O, 1]
    const float* sc_lo  = (const float*)d_in[4];  // [S, NB]
    const float* sc_hi  = (const float*)d_in[5];  // [S, 1]
    // d_in[6], d_in[7] (inp_base_lo/hi) unused by reference

    // workspace: A' 16 MB @ 0, B' 32 MB @ 16 MB (needs 48 MB of d_ws)
    unsigned short* A = (unsigned short*)d_ws;
    unsigned short* B = A + (size_t)S_DIM * K_DIM;

    prepass<<<XBLK + WBLK, 256, 0, stream>>>(x, sc_lo, sc_hi, weight, scales, keep, A, B);

    dim3 grid(O_DIM / BN, S_DIM / BM);
    gemm_bt<<<grid, 256, 0, stream>>>(A, B, (float*)d_out);
}